// Round 1
// baseline (1947.274 us; speedup 1.0000x reference)
//
#include <hip/hip_runtime.h>

#define NBINS 65536
#define IMG_HW 36864   // 192*192
#define NINST 32
#define CCH 16
#define NH 32
#define PADW 28672     // 256*256 - 192*192
#define NB 2
#define EPSF 1e-6f

typedef unsigned long long u64;

// ------------------------------------------------------------------
// Workspace layout (bytes):
//   wg      : NB*NBINS*8  = 1048576   (w in low32, gw in high32)
//   rsum    : NB*NBINS*4  =  524288
//   centers : NB*32*16*4  =    4096   (raw sums, then a = center/32)
//   q       : NB*32*32*4  =    8192
//   counts  : NB*32*4     =     256
//   meta    : 8*4                      [errlo, scale, maxa0, maxa1, G0, G1]
// ------------------------------------------------------------------
#define OFF_WG      0
#define OFF_RSUM    1048576
#define OFF_CENT    1572864
#define OFF_Q       1576960
#define OFF_CNT     1585152
#define OFF_META    1585408

// One block per (instance, image): deterministic masked sum of embeddings.
__global__ void k_centers(const float* __restrict__ emb, const int* __restrict__ gt,
                          float* __restrict__ centers, int* __restrict__ counts) {
    int n = blockIdx.x, b = blockIdx.y;
    const float* e = emb + (size_t)b * CCH * IMG_HW;
    const int* g = gt + (size_t)b * IMG_HW;
    float acc[CCH];
#pragma unroll
    for (int c = 0; c < CCH; c++) acc[c] = 0.f;
    int cnt = 0;
    int lbl = n + 1;
    for (int p = threadIdx.x; p < IMG_HW; p += 256) {
        if (g[p] == lbl) {
            cnt++;
#pragma unroll
            for (int c = 0; c < CCH; c++) acc[c] += e[c * IMG_HW + p];
        }
    }
#pragma unroll
    for (int off = 32; off > 0; off >>= 1) {
#pragma unroll
        for (int c = 0; c < CCH; c++) acc[c] += __shfl_down(acc[c], off, 64);
        cnt += __shfl_down(cnt, off, 64);
    }
    __shared__ float sred[4][CCH];
    __shared__ int scnt[4];
    int wid = threadIdx.x >> 6, lane = threadIdx.x & 63;
    if (lane == 0) {
#pragma unroll
        for (int c = 0; c < CCH; c++) sred[wid][c] = acc[c];
        scnt[wid] = cnt;
    }
    __syncthreads();
    if (threadIdx.x < CCH) {
        float s = sred[0][threadIdx.x] + sred[1][threadIdx.x] + sred[2][threadIdx.x] + sred[3][threadIdx.x];
        centers[((size_t)b * NINST + n) * CCH + threadIdx.x] = s;
    }
    if (threadIdx.x == CCH) counts[b * NINST + n] = scnt[0] + scnt[1] + scnt[2] + scnt[3];
}

// One block per image: finalize a = center/32, q = a@W1+b1, maxa, G, error
// range bound, and insert the (collapsed) padded-region items.
__global__ void k_finalize(const float* __restrict__ W1, const float* __restrict__ b1,
                           const float* __restrict__ W2, const float* __restrict__ b2,
                           float* __restrict__ centers, const int* __restrict__ counts,
                           float* __restrict__ qout, float* __restrict__ meta,
                           u64* __restrict__ wg, float* __restrict__ rsum) {
    int b = blockIdx.x;
    int tid = threadIdx.x;
    __shared__ float a_s[NINST][CCH];
    __shared__ float q_s[NINST][NH];
    __shared__ float red[4];
    __shared__ float sconst[2];

    for (int i = tid; i < NINST * CCH; i += 256) {
        int n = i / CCH, c = i % CCH;
        float cntf = (float)counts[b * NINST + n] + EPSF;
        float a = centers[((size_t)b * NINST + n) * CCH + c] / cntf * (1.f / 32.f);
        a_s[n][c] = a;
        centers[((size_t)b * NINST + n) * CCH + c] = a;
    }
    __syncthreads();
    for (int i = tid; i < NINST * NH; i += 256) {
        int n = i / NH, j = i % NH;
        float s = b1[j];
#pragma unroll
        for (int c = 0; c < CCH; c++) s += a_s[n][c] * W1[c * NH + j];
        q_s[n][j] = s;
        qout[((size_t)b * NINST + n) * NH + j] = s;
    }
    float ma = 0.f;
    for (int i = tid; i < NINST * CCH; i += 256) ma = fmaxf(ma, fabsf(a_s[i / CCH][i % CCH]));
#pragma unroll
    for (int off = 32; off > 0; off >>= 1) ma = fmaxf(ma, __shfl_down(ma, off, 64));
    if ((tid & 63) == 0) red[tid >> 6] = ma;
    __syncthreads();
    if (tid == 0) {
        float m = fmaxf(fmaxf(red[0], red[1]), fmaxf(red[2], red[3]));
        meta[2 + b] = m;
        int Gs = 0;
        for (int n = 0; n < NINST; n++) Gs += counts[b * NINST + n];
        meta[4 + b] = (float)Gs;
        // conservative bound L on |logit|
        float L = fabsf(b2[0]);
        for (int j = 0; j < NH; j++) {
            float sa = 0.f;
            for (int c = 0; c < CCH; c++) sa += fabsf(W1[c * NH + j]);
            float hmax = fmaxf(b1[j] + 2.f * sa, 0.f);
            L += hmax * fabsf(W2[j]);
        }
        L += 1.f;  // margin
        float errlo = 1.f - L;
        float scale = (float)NBINS / (2.f * L);
        meta[0] = errlo;
        meta[1] = scale;
        sconst[0] = errlo;
        sconst[1] = scale;
    }
    __syncthreads();
    // padded-region items: emb=0 there, label=0, weight PADW per instance.
    // exact: feats = clip(a, -2, 2)
    if (tid < NINST) {
        int n = tid;
        float logit = b2[0];
        for (int j = 0; j < NH; j++) {
            float s = b1[j];
#pragma unroll
            for (int c = 0; c < CCH; c++) {
                float f = fminf(fmaxf(a_s[n][c], -2.f), 2.f);
                s += f * W1[c * NH + j];
            }
            logit += fmaxf(s, 0.f) * W2[j];
        }
        float e = 1.f + logit;  // label 0 -> sign -1
        float errlo = sconst[0], scale = sconst[1];
        int bin = (int)((e - errlo) * scale);
        bin = min(max(bin, 0), NBINS - 1);
        atomicAdd(&wg[(size_t)b * NBINS + bin], (u64)PADW);
        atomicAdd(&rsum[(size_t)b * NBINS + bin], (float)PADW * fmaxf(e, 0.f));
    }
}

// One thread per interior pixel; loop over 32 instances; histogram the errors.
__global__ void k_hist(const float* __restrict__ emb, const int* __restrict__ gt,
                       const float* __restrict__ W1, const float* __restrict__ b1,
                       const float* __restrict__ W2, const float* __restrict__ b2,
                       const float* __restrict__ centers, const float* __restrict__ q,
                       const float* __restrict__ meta,
                       u64* __restrict__ wg, float* __restrict__ rsum) {
    int b = blockIdx.y;
    int tid = threadIdx.x;
    __shared__ float W1s[CCH][NH];
    __shared__ float q_s[NINST][NH];
    __shared__ float a_s[NINST][CCH];
    __shared__ float W2s[NH], b1s[NH];
    __shared__ float cons[4];
    for (int i = tid; i < CCH * NH; i += 256) W1s[i / NH][i % NH] = W1[i];
    for (int i = tid; i < NINST * NH; i += 256) q_s[i / NH][i % NH] = q[(size_t)b * NINST * NH + i];
    for (int i = tid; i < NINST * CCH; i += 256) a_s[i / CCH][i % CCH] = centers[(size_t)b * NINST * CCH + i];
    if (tid < NH) { W2s[tid] = W2[tid]; b1s[tid] = b1[tid]; }
    if (tid == 0) { cons[0] = b2[0]; cons[1] = meta[0]; cons[2] = meta[1]; cons[3] = meta[2 + b]; }
    __syncthreads();

    int pix = blockIdx.x * 256 + tid;
    const float* e = emb + (size_t)b * CCH * IMG_HW;
    int gtv = gt[(size_t)b * IMG_HW + pix];
    float u[CCH];
    float maxu = 0.f;
#pragma unroll
    for (int c = 0; c < CCH; c++) {
        u[c] = e[c * IMG_HW + pix] * (1.f / 32.f);
        maxu = fmaxf(maxu, fabsf(u[c]));
    }
    u64* wgb = wg + (size_t)b * NBINS;
    float* rsb = rsum + (size_t)b * NBINS;
    float b2v = cons[0], errlo = cons[1], scale = cons[2], maxa = cons[3];

    if (maxu + maxa <= 2.f) {
        // no element can clip: h = relu(q_n - v), v shared across instances
        float v[NH];
#pragma unroll
        for (int j = 0; j < NH; j++) {
            float s = 0.f;
#pragma unroll
            for (int c = 0; c < CCH; c++) s += u[c] * W1s[c][j];
            v[j] = s;
        }
        for (int n = 0; n < NINST; n++) {
            float logit = b2v;
#pragma unroll
            for (int j = 0; j < NH; j++) logit += fmaxf(q_s[n][j] - v[j], 0.f) * W2s[j];
            int label = (gtv == n + 1) ? 1 : 0;
            float er = label ? (1.f - logit) : (1.f + logit);
            int bin = (int)((er - errlo) * scale);
            bin = min(max(bin, 0), NBINS - 1);
            atomicAdd(&wgb[bin], 1ull | ((u64)label << 32));
            atomicAdd(&rsb[bin], fmaxf(er, 0.f));
        }
    } else {
        // exact slow path with per-element clip
        for (int n = 0; n < NINST; n++) {
            float logit = b2v;
            for (int j = 0; j < NH; j++) {
                float s = b1s[j];
#pragma unroll
                for (int c = 0; c < CCH; c++) {
                    float f = fminf(fmaxf(a_s[n][c] - u[c], -2.f), 2.f);
                    s += f * W1s[c][j];
                }
                logit += fmaxf(s, 0.f) * W2s[j];
            }
            int label = (gtv == n + 1) ? 1 : 0;
            float er = label ? (1.f - logit) : (1.f + logit);
            int bin = (int)((er - errlo) * scale);
            bin = min(max(bin, 0), NBINS - 1);
            atomicAdd(&wgb[bin], 1ull | ((u64)label << 32));
            atomicAdd(&rsb[bin], fmaxf(er, 0.f));
        }
    }
}

// One block per image: scan bins in descending-error order, telescoping
// Jaccard contributions per bin. Each thread owns 64 consecutive bins.
__global__ void k_loss(const u64* __restrict__ wg, const float* __restrict__ rsum,
                       const float* __restrict__ meta, float* __restrict__ out) {
    int b = blockIdx.x;
    int tid = threadIdx.x;
    const u64* wgb = wg + (size_t)b * NBINS;
    const float* rsb = rsum + (size_t)b * NBINS;
    double G = (double)meta[4 + b];

    // pass 1: per-thread packed totals over its 64 bins
    u64 tot = 0;
    for (int k = 0; k < 64; k++) {
        int bin = NBINS - 1 - (tid * 64 + k);
        tot += wgb[bin];
    }
    // wave-level inclusive scan
    u64 incl = tot;
    int lane = tid & 63, wid = tid >> 6;
#pragma unroll
    for (int off = 1; off < 64; off <<= 1) {
        u64 x = __shfl_up(incl, off, 64);
        if (lane >= off) incl += x;
    }
    __shared__ u64 wpart[16];
    __shared__ double lossred[16];
    if (lane == 63) wpart[wid] = incl;
    __syncthreads();
    u64 woff = 0;
    for (int w = 0; w < wid; w++) woff += wpart[w];
    u64 excl = woff + incl - tot;
    unsigned int p = (unsigned int)(excl & 0xffffffffull);
    unsigned int cs = (unsigned int)(excl >> 32);

    // pass 2: contributions
    double loss = 0.0;
    if (G > 0.5) {
        for (int k = 0; k < 64; k++) {
            int bin = NBINS - 1 - (tid * 64 + k);
            u64 v = wgb[bin];
            unsigned int w = (unsigned int)(v & 0xffffffffull);
            unsigned int g = (unsigned int)(v >> 32);
            if (w) {
                double Js = 1.0 - (G - (double)cs) / (G + (double)p - (double)cs);
                unsigned int pe = p + w, ce = cs + g;
                double Je = 1.0 - (G - (double)ce) / (G + (double)pe - (double)ce);
                double rbar = (double)rsb[bin] / (double)w;
                loss += rbar * (Je - Js);
                p = pe;
                cs = ce;
            }
        }
    }
#pragma unroll
    for (int off = 32; off > 0; off >>= 1) loss += __shfl_down(loss, off, 64);
    if (lane == 0) lossred[wid] = loss;
    __syncthreads();
    if (tid == 0) {
        double t = 0;
        for (int w = 0; w < 16; w++) t += lossred[w];
        atomicAdd(out, (float)(t * 0.5));  // mean over 2 images
    }
}

extern "C" void kernel_launch(void* const* d_in, const int* in_sizes, int n_in,
                              void* d_out, int out_size, void* d_ws, size_t ws_size,
                              hipStream_t stream) {
    const float* emb = (const float*)d_in[0];
    const int* gt = (const int*)d_in[1];
    const float* W1 = (const float*)d_in[2];
    const float* b1 = (const float*)d_in[3];
    const float* W2 = (const float*)d_in[4];
    const float* b2 = (const float*)d_in[5];
    float* out = (float*)d_out;
    char* ws = (char*)d_ws;

    u64* wg = (u64*)(ws + OFF_WG);
    float* rsum = (float*)(ws + OFF_RSUM);
    float* centers = (float*)(ws + OFF_CENT);
    float* q = (float*)(ws + OFF_Q);
    int* counts = (int*)(ws + OFF_CNT);
    float* meta = (float*)(ws + OFF_META);

    hipMemsetAsync(ws, 0, OFF_CENT, stream);      // wg + rsum
    hipMemsetAsync(d_out, 0, sizeof(float), stream);

    k_centers<<<dim3(NINST, NB), 256, 0, stream>>>(emb, gt, centers, counts);
    k_finalize<<<dim3(NB), 256, 0, stream>>>(W1, b1, W2, b2, centers, counts, q, meta, wg, rsum);
    k_hist<<<dim3(IMG_HW / 256, NB), 256, 0, stream>>>(emb, gt, W1, b1, W2, b2, centers, q, meta, wg, rsum);
    k_loss<<<dim3(NB), 1024, 0, stream>>>(wg, rsum, meta, out);
}

// Round 2
// 182.011 us; speedup vs baseline: 10.6986x; 10.6986x over previous
//
#include <hip/hip_runtime.h>

#define NBINS 16384
#define IMG_HW 36864   // 192*192
#define NINST 32
#define CCH 16
#define NH 32
#define PADW 28672     // 256*256 - 192*192
#define NB 2
#define EPSF 1e-6f

typedef unsigned long long u64;

// ------------------------------------------------------------------
// Workspace layout (bytes):
//   wg      : NB*NBINS*8  = 262144   (w in low32, gw in high32)
//   centers : NB*32*16*4  =   4096
//   q       : NB*32*32*4  =   8192
//   counts  : NB*32*4     =    256
//   meta    : 8*4                      [errlo, scale, maxa0, maxa1, G0, G1]
// ------------------------------------------------------------------
#define OFF_WG      0
#define OFF_CENT    262144
#define OFF_Q       266240
#define OFF_CNT     274432
#define OFF_META    274688

// One block per (instance, image): deterministic masked sum of embeddings.
__global__ void k_centers(const float* __restrict__ emb, const int* __restrict__ gt,
                          float* __restrict__ centers, int* __restrict__ counts) {
    int n = blockIdx.x, b = blockIdx.y;
    const float* e = emb + (size_t)b * CCH * IMG_HW;
    const int* g = gt + (size_t)b * IMG_HW;
    float acc[CCH];
#pragma unroll
    for (int c = 0; c < CCH; c++) acc[c] = 0.f;
    int cnt = 0;
    int lbl = n + 1;
    for (int p = threadIdx.x; p < IMG_HW; p += 256) {
        if (g[p] == lbl) {
            cnt++;
#pragma unroll
            for (int c = 0; c < CCH; c++) acc[c] += e[c * IMG_HW + p];
        }
    }
#pragma unroll
    for (int off = 32; off > 0; off >>= 1) {
#pragma unroll
        for (int c = 0; c < CCH; c++) acc[c] += __shfl_down(acc[c], off, 64);
        cnt += __shfl_down(cnt, off, 64);
    }
    __shared__ float sred[4][CCH];
    __shared__ int scnt[4];
    int wid = threadIdx.x >> 6, lane = threadIdx.x & 63;
    if (lane == 0) {
#pragma unroll
        for (int c = 0; c < CCH; c++) sred[wid][c] = acc[c];
        scnt[wid] = cnt;
    }
    __syncthreads();
    if (threadIdx.x < CCH) {
        float s = sred[0][threadIdx.x] + sred[1][threadIdx.x] + sred[2][threadIdx.x] + sred[3][threadIdx.x];
        centers[((size_t)b * NINST + n) * CCH + threadIdx.x] = s;
    }
    if (threadIdx.x == CCH) counts[b * NINST + n] = scnt[0] + scnt[1] + scnt[2] + scnt[3];
}

// One block per image: finalize a = center/32, q = a@W1+b1, maxa, G, error
// range bound, and insert the (collapsed) padded-region items.
__global__ void k_finalize(const float* __restrict__ W1, const float* __restrict__ b1,
                           const float* __restrict__ W2, const float* __restrict__ b2,
                           float* __restrict__ centers, const int* __restrict__ counts,
                           float* __restrict__ qout, float* __restrict__ meta,
                           u64* __restrict__ wg) {
    int b = blockIdx.x;
    int tid = threadIdx.x;
    __shared__ float a_s[NINST][CCH];
    __shared__ float red[4];
    __shared__ float sconst[2];

    for (int i = tid; i < NINST * CCH; i += 256) {
        int n = i / CCH, c = i % CCH;
        float cntf = (float)counts[b * NINST + n] + EPSF;
        float a = centers[((size_t)b * NINST + n) * CCH + c] / cntf * (1.f / 32.f);
        a_s[n][c] = a;
        centers[((size_t)b * NINST + n) * CCH + c] = a;
    }
    __syncthreads();
    for (int i = tid; i < NINST * NH; i += 256) {
        int n = i / NH, j = i % NH;
        float s = b1[j];
#pragma unroll
        for (int c = 0; c < CCH; c++) s += a_s[n][c] * W1[c * NH + j];
        qout[((size_t)b * NINST + n) * NH + j] = s;
    }
    float ma = 0.f;
    for (int i = tid; i < NINST * CCH; i += 256) ma = fmaxf(ma, fabsf(a_s[i / CCH][i % CCH]));
#pragma unroll
    for (int off = 32; off > 0; off >>= 1) ma = fmaxf(ma, __shfl_down(ma, off, 64));
    if ((tid & 63) == 0) red[tid >> 6] = ma;
    __syncthreads();
    if (tid == 0) {
        float m = fmaxf(fmaxf(red[0], red[1]), fmaxf(red[2], red[3]));
        meta[2 + b] = m;
        int Gs = 0;
        for (int n = 0; n < NINST; n++) Gs += counts[b * NINST + n];
        meta[4 + b] = (float)Gs;
        // conservative bound L on |logit|
        float L = fabsf(b2[0]);
        for (int j = 0; j < NH; j++) {
            float sa = 0.f;
            for (int c = 0; c < CCH; c++) sa += fabsf(W1[c * NH + j]);
            float hmax = fmaxf(b1[j] + 2.f * sa, 0.f);
            L += hmax * fabsf(W2[j]);
        }
        L += 1.f;  // margin
        float errlo = 1.f - L;
        float scale = (float)NBINS / (2.f * L);
        meta[0] = errlo;
        meta[1] = scale;
        sconst[0] = errlo;
        sconst[1] = scale;
    }
    __syncthreads();
    // padded-region items: emb=0 there, label=0, weight PADW per instance.
    // exact: feats = clip(a, -2, 2)
    if (tid < NINST) {
        int n = tid;
        float logit = b2[0];
        for (int j = 0; j < NH; j++) {
            float s = b1[j];
#pragma unroll
            for (int c = 0; c < CCH; c++) {
                float f = fminf(fmaxf(a_s[n][c], -2.f), 2.f);
                s += f * W1[c * NH + j];
            }
            logit += fmaxf(s, 0.f) * W2[j];
        }
        float e = 1.f + logit;  // label 0 -> sign -1
        float errlo = sconst[0], scale = sconst[1];
        int bin = (int)((e - errlo) * scale);
        bin = min(max(bin, 0), NBINS - 1);
        atomicAdd(&wg[(size_t)b * NBINS + bin], (u64)PADW);
    }
}

// One thread per interior pixel; loop over 32 instances; LDS-private
// histogram per block, single flush to global at the end.
// Small uniform tables (W1,b1,W2,b2,q,centers,meta) are read directly from
// global (wave-uniform -> s_load, L2-hot) to leave all 64KB LDS for the hist.
__global__ void __launch_bounds__(256, 2)
k_hist(const float* __restrict__ emb, const int* __restrict__ gt,
       const float* __restrict__ W1, const float* __restrict__ b1,
       const float* __restrict__ W2, const float* __restrict__ b2,
       const float* __restrict__ centers, const float* __restrict__ q,
       const float* __restrict__ meta,
       u64* __restrict__ wg) {
    __shared__ unsigned int hist[NBINS];  // 64 KB: w in low16, g in high16
    int b = blockIdx.y;
    int tid = threadIdx.x;
    for (int i = tid; i < NBINS; i += 256) hist[i] = 0u;
    __syncthreads();

    int pix = blockIdx.x * 256 + tid;
    const float* e = emb + (size_t)b * CCH * IMG_HW;
    int gtv = gt[(size_t)b * IMG_HW + pix];
    float u[CCH];
    float maxu = 0.f;
#pragma unroll
    for (int c = 0; c < CCH; c++) {
        u[c] = e[c * IMG_HW + pix] * (1.f / 32.f);
        maxu = fmaxf(maxu, fabsf(u[c]));
    }
    float b2v = b2[0];
    float errlo = meta[0], scale = meta[1], maxa = meta[2 + b];
    const float* qb = q + (size_t)b * NINST * NH;
    const float* ab = centers + (size_t)b * NINST * CCH;

    if (maxu + maxa <= 2.f) {
        // no element can clip: h = relu(q_n - v), v shared across instances
        float v[NH];
#pragma unroll
        for (int j = 0; j < NH; j++) {
            float s = 0.f;
#pragma unroll
            for (int c = 0; c < CCH; c++) s += u[c] * W1[c * NH + j];
            v[j] = s;
        }
        for (int n = 0; n < NINST; n++) {
            float logit = b2v;
#pragma unroll
            for (int j = 0; j < NH; j++) logit += fmaxf(qb[n * NH + j] - v[j], 0.f) * W2[j];
            unsigned int label = (gtv == n + 1) ? 1u : 0u;
            float er = label ? (1.f - logit) : (1.f + logit);
            int bin = (int)((er - errlo) * scale);
            bin = min(max(bin, 0), NBINS - 1);
            atomicAdd(&hist[bin], 1u | (label << 16));
        }
    } else {
        // exact slow path with per-element clip
        for (int n = 0; n < NINST; n++) {
            float logit = b2v;
            for (int j = 0; j < NH; j++) {
                float s = b1[j];
#pragma unroll
                for (int c = 0; c < CCH; c++) {
                    float f = fminf(fmaxf(ab[n * CCH + c] - u[c], -2.f), 2.f);
                    s += f * W1[c * NH + j];
                }
                logit += fmaxf(s, 0.f) * W2[j];
            }
            unsigned int label = (gtv == n + 1) ? 1u : 0u;
            float er = label ? (1.f - logit) : (1.f + logit);
            int bin = (int)((er - errlo) * scale);
            bin = min(max(bin, 0), NBINS - 1);
            atomicAdd(&hist[bin], 1u | (label << 16));
        }
    }
    __syncthreads();
    // flush nonzero bins to the global packed-u64 histogram
    u64* wgb = wg + (size_t)b * NBINS;
    for (int i = tid; i < NBINS; i += 256) {
        unsigned int h = hist[i];
        if (h) atomicAdd(&wgb[i], (u64)(h & 0xffffu) | ((u64)(h >> 16) << 32));
    }
}

// One block per image: scan bins in descending-error order, telescoping
// Jaccard contributions per bin. Each thread owns 16 consecutive bins.
// Per-bin representative error = bin center (error <= binwidth/2 ~ 2.6e-3).
__global__ void k_loss(const u64* __restrict__ wg,
                       const float* __restrict__ meta, float* __restrict__ out) {
    int b = blockIdx.x;
    int tid = threadIdx.x;
    const u64* wgb = wg + (size_t)b * NBINS;
    double G = (double)meta[4 + b];
    double errlo = (double)meta[0];
    double invscale = 1.0 / (double)meta[1];
    const int BPT = NBINS / 1024;

    // pass 1: per-thread packed totals over its BPT bins
    u64 tot = 0;
    for (int k = 0; k < BPT; k++) {
        int bin = NBINS - 1 - (tid * BPT + k);
        tot += wgb[bin];
    }
    // wave-level inclusive scan
    u64 incl = tot;
    int lane = tid & 63, wid = tid >> 6;
#pragma unroll
    for (int off = 1; off < 64; off <<= 1) {
        u64 x = __shfl_up(incl, off, 64);
        if (lane >= off) incl += x;
    }
    __shared__ u64 wpart[16];
    __shared__ double lossred[16];
    if (lane == 63) wpart[wid] = incl;
    __syncthreads();
    u64 woff = 0;
    for (int w = 0; w < wid; w++) woff += wpart[w];
    u64 excl = woff + incl - tot;
    unsigned int p = (unsigned int)(excl & 0xffffffffull);
    unsigned int cs = (unsigned int)(excl >> 32);

    // pass 2: contributions
    double loss = 0.0;
    if (G > 0.5) {
        for (int k = 0; k < BPT; k++) {
            int bin = NBINS - 1 - (tid * BPT + k);
            u64 v = wgb[bin];
            unsigned int w = (unsigned int)(v & 0xffffffffull);
            unsigned int g = (unsigned int)(v >> 32);
            if (w) {
                double Js = 1.0 - (G - (double)cs) / (G + (double)p - (double)cs);
                unsigned int pe = p + w, ce = cs + g;
                double Je = 1.0 - (G - (double)ce) / (G + (double)pe - (double)ce);
                double rep = errlo + ((double)bin + 0.5) * invscale;
                if (rep < 0.0) rep = 0.0;
                loss += rep * (Je - Js);
                p = pe;
                cs = ce;
            }
        }
    }
#pragma unroll
    for (int off = 32; off > 0; off >>= 1) loss += __shfl_down(loss, off, 64);
    if (lane == 0) lossred[wid] = loss;
    __syncthreads();
    if (tid == 0) {
        double t = 0;
        for (int w = 0; w < 16; w++) t += lossred[w];
        atomicAdd(out, (float)(t * 0.5));  // mean over 2 images
    }
}

extern "C" void kernel_launch(void* const* d_in, const int* in_sizes, int n_in,
                              void* d_out, int out_size, void* d_ws, size_t ws_size,
                              hipStream_t stream) {
    const float* emb = (const float*)d_in[0];
    const int* gt = (const int*)d_in[1];
    const float* W1 = (const float*)d_in[2];
    const float* b1 = (const float*)d_in[3];
    const float* W2 = (const float*)d_in[4];
    const float* b2 = (const float*)d_in[5];
    float* out = (float*)d_out;
    char* ws = (char*)d_ws;

    u64* wg = (u64*)(ws + OFF_WG);
    float* centers = (float*)(ws + OFF_CENT);
    float* q = (float*)(ws + OFF_Q);
    int* counts = (int*)(ws + OFF_CNT);
    float* meta = (float*)(ws + OFF_META);

    hipMemsetAsync(ws, 0, OFF_CENT, stream);      // wg
    hipMemsetAsync(d_out, 0, sizeof(float), stream);

    k_centers<<<dim3(NINST, NB), 256, 0, stream>>>(emb, gt, centers, counts);
    k_finalize<<<dim3(NB), 256, 0, stream>>>(W1, b1, W2, b2, centers, counts, q, meta, wg);
    k_hist<<<dim3(IMG_HW / 256, NB), 256, 0, stream>>>(emb, gt, W1, b1, W2, b2, centers, q, meta, wg);
    k_loss<<<dim3(NB), 1024, 0, stream>>>(wg, meta, out);
}

// Round 3
// 84.861 us; speedup vs baseline: 22.9467x; 2.1448x over previous
//
#include <hip/hip_runtime.h>

#define NBINS 16384
#define IMG_HW 36864   // 192*192
#define NPIXBLK 144    // IMG_HW / 256
#define NINST 32
#define CCH 16
#define NH 32
#define PADW 28672     // 256*256 - 192*192
#define NB 2
#define EPSF 1e-6f
#define NACC (NINST * (CCH + 1))   // 544: 512 channel sums + 32 counts

typedef unsigned long long u64;
typedef long long i64;

// ------------------------------------------------------------------
// Workspace layout (bytes):
//   wg       : NB*NBINS*8        =  262144  (w in low32, gw in high32)
//   partials : NB*144*544*8      = 1253376  (i64 fixed-point x 2^32)
//   centers  : NB*32*16*4        =    4096
//   q        : NB*32*32*4        =    8192
//   counts   : NB*32*4           =     256
//   meta     : 8*4                          [errlo, scale, maxa0, maxa1, G0, G1]
// ------------------------------------------------------------------
#define OFF_WG      0
#define OFF_PART    262144
#define OFF_CENT    1515520
#define OFF_Q       1519616
#define OFF_CNT     1527808
#define OFF_META    1528064

// Single pass over pixels: scatter each pixel's embedding into its own
// instance's LDS accumulator (i64 fixed-point => order-invariant,
// bit-deterministic), then dump per-block partials.
__global__ void k_centers(const float* __restrict__ emb, const int* __restrict__ gt,
                          i64* __restrict__ partials) {
    int blk = blockIdx.x, b = blockIdx.y;
    int tid = threadIdx.x;
    __shared__ i64 acc[NACC];
    for (int i = tid; i < NACC; i += 256) acc[i] = 0;
    __syncthreads();

    int pix = blk * 256 + tid;
    int gtv = gt[(size_t)b * IMG_HW + pix];
    if (gtv > 0) {
        int n = gtv - 1;
        const float* e = emb + (size_t)b * CCH * IMG_HW + pix;
#pragma unroll
        for (int c = 0; c < CCH; c++) {
            i64 fx = (i64)((double)e[c * IMG_HW] * 4294967296.0);
            atomicAdd((u64*)&acc[n * CCH + c], (u64)fx);
        }
        atomicAdd((u64*)&acc[NINST * CCH + n], 1ull);
    }
    __syncthreads();
    i64* pb = partials + ((size_t)b * NPIXBLK + blk) * NACC;
    for (int i = tid; i < NACC; i += 256) pb[i] = acc[i];
}

// One block per image: reduce partials (fixed order, exact integer adds),
// then a = center/32, q = a@W1+b1, maxa, G, error range bound, and the
// (collapsed) padded-region items.
__global__ void k_finalize(const float* __restrict__ W1, const float* __restrict__ b1,
                           const float* __restrict__ W2, const float* __restrict__ b2,
                           const i64* __restrict__ partials,
                           float* __restrict__ centers, float* __restrict__ countsf,
                           float* __restrict__ qout, float* __restrict__ meta,
                           u64* __restrict__ wg) {
    int b = blockIdx.x;
    int tid = threadIdx.x;
    __shared__ i64 sum_s[NACC];
    __shared__ float a_s[NINST][CCH];
    __shared__ float red[4];
    __shared__ float sconst[2];

    for (int i = tid; i < NACC; i += 256) {
        i64 s = 0;
        const i64* pp = partials + (size_t)b * NPIXBLK * NACC + i;
        for (int p = 0; p < NPIXBLK; p++) s += pp[(size_t)p * NACC];
        sum_s[i] = s;
    }
    __syncthreads();

    for (int i = tid; i < NINST * CCH; i += 256) {
        int n = i / CCH, c = i % CCH;
        float cntf = (float)sum_s[NINST * CCH + n] + EPSF;
        float raw = (float)((double)sum_s[i] * (1.0 / 4294967296.0));
        float a = raw / cntf * (1.f / 32.f);
        a_s[n][c] = a;
        centers[((size_t)b * NINST + n) * CCH + c] = a;
    }
    if (tid < NINST) countsf[b * NINST + tid] = (float)sum_s[NINST * CCH + tid];
    __syncthreads();

    for (int i = tid; i < NINST * NH; i += 256) {
        int n = i / NH, j = i % NH;
        float s = b1[j];
#pragma unroll
        for (int c = 0; c < CCH; c++) s += a_s[n][c] * W1[c * NH + j];
        qout[((size_t)b * NINST + n) * NH + j] = s;
    }
    float ma = 0.f;
    for (int i = tid; i < NINST * CCH; i += 256) ma = fmaxf(ma, fabsf(a_s[i / CCH][i % CCH]));
#pragma unroll
    for (int off = 32; off > 0; off >>= 1) ma = fmaxf(ma, __shfl_down(ma, off, 64));
    if ((tid & 63) == 0) red[tid >> 6] = ma;
    __syncthreads();
    if (tid == 0) {
        float m = fmaxf(fmaxf(red[0], red[1]), fmaxf(red[2], red[3]));
        meta[2 + b] = m;
        float Gs = 0.f;
        for (int n = 0; n < NINST; n++) Gs += (float)sum_s[NINST * CCH + n];
        meta[4 + b] = Gs;
        // conservative bound L on |logit|
        float L = fabsf(b2[0]);
        for (int j = 0; j < NH; j++) {
            float sa = 0.f;
            for (int c = 0; c < CCH; c++) sa += fabsf(W1[c * NH + j]);
            float hmax = fmaxf(b1[j] + 2.f * sa, 0.f);
            L += hmax * fabsf(W2[j]);
        }
        L += 1.f;  // margin
        float errlo = 1.f - L;
        float scale = (float)NBINS / (2.f * L);
        meta[0] = errlo;
        meta[1] = scale;
        sconst[0] = errlo;
        sconst[1] = scale;
    }
    __syncthreads();
    // padded-region items: emb=0 there, label=0, weight PADW per instance.
    // exact: feats = clip(a, -2, 2)
    if (tid < NINST) {
        int n = tid;
        float logit = b2[0];
        for (int j = 0; j < NH; j++) {
            float s = b1[j];
#pragma unroll
            for (int c = 0; c < CCH; c++) {
                float f = fminf(fmaxf(a_s[n][c], -2.f), 2.f);
                s += f * W1[c * NH + j];
            }
            logit += fmaxf(s, 0.f) * W2[j];
        }
        float e = 1.f + logit;  // label 0 -> sign -1
        float errlo = sconst[0], scale = sconst[1];
        int bin = (int)((e - errlo) * scale);
        bin = min(max(bin, 0), NBINS - 1);
        atomicAdd(&wg[(size_t)b * NBINS + bin], (u64)PADW);
    }
}

// One thread per interior pixel; loop over 32 instances; LDS-private
// histogram per block, single flush to global at the end.
// Small uniform tables (W1,b1,W2,b2,q,centers,meta) are read directly from
// global (wave-uniform -> s_load, L2-hot) to leave all 64KB LDS for the hist.
__global__ void __launch_bounds__(256, 2)
k_hist(const float* __restrict__ emb, const int* __restrict__ gt,
       const float* __restrict__ W1, const float* __restrict__ b1,
       const float* __restrict__ W2, const float* __restrict__ b2,
       const float* __restrict__ centers, const float* __restrict__ q,
       const float* __restrict__ meta,
       u64* __restrict__ wg) {
    __shared__ unsigned int hist[NBINS];  // 64 KB: w in low16, g in high16
    int b = blockIdx.y;
    int tid = threadIdx.x;
    for (int i = tid; i < NBINS; i += 256) hist[i] = 0u;
    __syncthreads();

    int pix = blockIdx.x * 256 + tid;
    const float* e = emb + (size_t)b * CCH * IMG_HW;
    int gtv = gt[(size_t)b * IMG_HW + pix];
    float u[CCH];
    float maxu = 0.f;
#pragma unroll
    for (int c = 0; c < CCH; c++) {
        u[c] = e[c * IMG_HW + pix] * (1.f / 32.f);
        maxu = fmaxf(maxu, fabsf(u[c]));
    }
    float b2v = b2[0];
    float errlo = meta[0], scale = meta[1], maxa = meta[2 + b];
    const float* qb = q + (size_t)b * NINST * NH;
    const float* ab = centers + (size_t)b * NINST * CCH;

    if (maxu + maxa <= 2.f) {
        // no element can clip: h = relu(q_n - v), v shared across instances
        float v[NH];
#pragma unroll
        for (int j = 0; j < NH; j++) {
            float s = 0.f;
#pragma unroll
            for (int c = 0; c < CCH; c++) s += u[c] * W1[c * NH + j];
            v[j] = s;
        }
        for (int n = 0; n < NINST; n++) {
            float logit = b2v;
#pragma unroll
            for (int j = 0; j < NH; j++) logit += fmaxf(qb[n * NH + j] - v[j], 0.f) * W2[j];
            unsigned int label = (gtv == n + 1) ? 1u : 0u;
            float er = label ? (1.f - logit) : (1.f + logit);
            int bin = (int)((er - errlo) * scale);
            bin = min(max(bin, 0), NBINS - 1);
            atomicAdd(&hist[bin], 1u | (label << 16));
        }
    } else {
        // exact slow path with per-element clip
        for (int n = 0; n < NINST; n++) {
            float logit = b2v;
            for (int j = 0; j < NH; j++) {
                float s = b1[j];
#pragma unroll
                for (int c = 0; c < CCH; c++) {
                    float f = fminf(fmaxf(ab[n * CCH + c] - u[c], -2.f), 2.f);
                    s += f * W1[c * NH + j];
                }
                logit += fmaxf(s, 0.f) * W2[j];
            }
            unsigned int label = (gtv == n + 1) ? 1u : 0u;
            float er = label ? (1.f - logit) : (1.f + logit);
            int bin = (int)((er - errlo) * scale);
            bin = min(max(bin, 0), NBINS - 1);
            atomicAdd(&hist[bin], 1u | (label << 16));
        }
    }
    __syncthreads();
    // flush nonzero bins to the global packed-u64 histogram
    u64* wgb = wg + (size_t)b * NBINS;
    for (int i = tid; i < NBINS; i += 256) {
        unsigned int h = hist[i];
        if (h) atomicAdd(&wgb[i], (u64)(h & 0xffffu) | ((u64)(h >> 16) << 32));
    }
}

// One block per image: scan bins in descending-error order, telescoping
// Jaccard contributions per bin. Each thread owns 16 consecutive bins.
// Per-bin representative error = bin center (error <= binwidth/2 ~ 2.6e-3).
__global__ void k_loss(const u64* __restrict__ wg,
                       const float* __restrict__ meta, float* __restrict__ out) {
    int b = blockIdx.x;
    int tid = threadIdx.x;
    const u64* wgb = wg + (size_t)b * NBINS;
    double G = (double)meta[4 + b];
    double errlo = (double)meta[0];
    double invscale = 1.0 / (double)meta[1];
    const int BPT = NBINS / 1024;

    // pass 1: per-thread packed totals over its BPT bins
    u64 tot = 0;
    for (int k = 0; k < BPT; k++) {
        int bin = NBINS - 1 - (tid * BPT + k);
        tot += wgb[bin];
    }
    // wave-level inclusive scan
    u64 incl = tot;
    int lane = tid & 63, wid = tid >> 6;
#pragma unroll
    for (int off = 1; off < 64; off <<= 1) {
        u64 x = __shfl_up(incl, off, 64);
        if (lane >= off) incl += x;
    }
    __shared__ u64 wpart[16];
    __shared__ double lossred[16];
    if (lane == 63) wpart[wid] = incl;
    __syncthreads();
    u64 woff = 0;
    for (int w = 0; w < wid; w++) woff += wpart[w];
    u64 excl = woff + incl - tot;
    unsigned int p = (unsigned int)(excl & 0xffffffffull);
    unsigned int cs = (unsigned int)(excl >> 32);

    // pass 2: contributions
    double loss = 0.0;
    if (G > 0.5) {
        for (int k = 0; k < BPT; k++) {
            int bin = NBINS - 1 - (tid * BPT + k);
            u64 v = wgb[bin];
            unsigned int w = (unsigned int)(v & 0xffffffffull);
            unsigned int g = (unsigned int)(v >> 32);
            if (w) {
                double Js = 1.0 - (G - (double)cs) / (G + (double)p - (double)cs);
                unsigned int pe = p + w, ce = cs + g;
                double Je = 1.0 - (G - (double)ce) / (G + (double)pe - (double)ce);
                double rep = errlo + ((double)bin + 0.5) * invscale;
                if (rep < 0.0) rep = 0.0;
                loss += rep * (Je - Js);
                p = pe;
                cs = ce;
            }
        }
    }
#pragma unroll
    for (int off = 32; off > 0; off >>= 1) loss += __shfl_down(loss, off, 64);
    if (lane == 0) lossred[wid] = loss;
    __syncthreads();
    if (tid == 0) {
        double t = 0;
        for (int w = 0; w < 16; w++) t += lossred[w];
        atomicAdd(out, (float)(t * 0.5));  // mean over 2 images
    }
}

extern "C" void kernel_launch(void* const* d_in, const int* in_sizes, int n_in,
                              void* d_out, int out_size, void* d_ws, size_t ws_size,
                              hipStream_t stream) {
    const float* emb = (const float*)d_in[0];
    const int* gt = (const int*)d_in[1];
    const float* W1 = (const float*)d_in[2];
    const float* b1 = (const float*)d_in[3];
    const float* W2 = (const float*)d_in[4];
    const float* b2 = (const float*)d_in[5];
    float* out = (float*)d_out;
    char* ws = (char*)d_ws;

    u64* wg = (u64*)(ws + OFF_WG);
    i64* partials = (i64*)(ws + OFF_PART);
    float* centers = (float*)(ws + OFF_CENT);
    float* q = (float*)(ws + OFF_Q);
    float* countsf = (float*)(ws + OFF_CNT);
    float* meta = (float*)(ws + OFF_META);

    hipMemsetAsync(ws, 0, OFF_PART, stream);      // wg only
    hipMemsetAsync(d_out, 0, sizeof(float), stream);

    k_centers<<<dim3(NPIXBLK, NB), 256, 0, stream>>>(emb, gt, partials);
    k_finalize<<<dim3(NB), 256, 0, stream>>>(W1, b1, W2, b2, partials, centers, countsf, q, meta, wg);
    k_hist<<<dim3(NPIXBLK, NB), 256, 0, stream>>>(emb, gt, W1, b1, W2, b2, centers, q, meta, wg);
    k_loss<<<dim3(NB), 1024, 0, stream>>>(wg, meta, out);
}

// Round 4
// 78.021 us; speedup vs baseline: 24.9583x; 1.0877x over previous
//
#include <hip/hip_runtime.h>

#define NBINS 16384
#define IMG_HW 36864   // 192*192
#define NPIXBLK 144    // IMG_HW / 256
#define NINST 32
#define CCH 16
#define NH 32
#define PADW 28672     // 256*256 - 192*192
#define NB 2
#define EPSF 1e-6f
#define NACC (NINST * (CCH + 1))   // 544: 512 channel sums + 32 counts

typedef unsigned long long u64;
typedef long long i64;

// ------------------------------------------------------------------
// Workspace layout (bytes):
//   wg       : NB*NBINS*8        =  262144  (w in low32, gw in high32)
//   partials : NB*144*544*8      = 1253376  (i64 fixed-point x 2^32)
//   centers  : NB*32*16*4        =    4096
//   q        : NB*32*32*4        =    8192
//   counts   : NB*32*4           =     256
//   meta     : 8*4                          [errlo, scale, maxa0, maxa1, G0, G1]
// ------------------------------------------------------------------
#define OFF_WG      0
#define OFF_PART    262144
#define OFF_CENT    1515520
#define OFF_Q       1519616
#define OFF_CNT     1527808
#define OFF_META    1528064

// Single pass over pixels: scatter each pixel's embedding into its own
// instance's LDS accumulator (i64 fixed-point => order-invariant,
// bit-deterministic), then dump per-block partials.
// Also zeroes wg and out (replaces two hipMemsetAsync graph nodes, each of
// which cost ~40us of fixed fill-dispatch overhead).
__global__ void k_centers(const float* __restrict__ emb, const int* __restrict__ gt,
                          i64* __restrict__ partials, u64* __restrict__ wg,
                          float* __restrict__ out) {
    int blk = blockIdx.x, b = blockIdx.y;
    int tid = threadIdx.x;
    __shared__ i64 acc[NACC];
    for (int i = tid; i < NACC; i += 256) acc[i] = 0;

    // zero the global histogram + output (stream order guarantees visibility
    // to the later kernels; k_centers itself never touches wg/out again)
    int gid = ((b * NPIXBLK) + blk) * 256 + tid;
    if (gid < NB * NBINS) wg[gid] = 0ull;
    if (gid == 0) out[0] = 0.f;
    __syncthreads();

    int pix = blk * 256 + tid;
    int gtv = gt[(size_t)b * IMG_HW + pix];
    if (gtv > 0) {
        int n = gtv - 1;
        const float* e = emb + (size_t)b * CCH * IMG_HW + pix;
#pragma unroll
        for (int c = 0; c < CCH; c++) {
            i64 fx = (i64)((double)e[c * IMG_HW] * 4294967296.0);
            atomicAdd((u64*)&acc[n * CCH + c], (u64)fx);
        }
        atomicAdd((u64*)&acc[NINST * CCH + n], 1ull);
    }
    __syncthreads();
    i64* pb = partials + ((size_t)b * NPIXBLK + blk) * NACC;
    for (int i = tid; i < NACC; i += 256) pb[i] = acc[i];
}

// One block per image: reduce partials (fixed order, exact integer adds),
// then a = center/32, q = a@W1+b1, maxa, G, error range bound, and the
// (collapsed) padded-region items.
__global__ void k_finalize(const float* __restrict__ W1, const float* __restrict__ b1,
                           const float* __restrict__ W2, const float* __restrict__ b2,
                           const i64* __restrict__ partials,
                           float* __restrict__ centers, float* __restrict__ countsf,
                           float* __restrict__ qout, float* __restrict__ meta,
                           u64* __restrict__ wg) {
    int b = blockIdx.x;
    int tid = threadIdx.x;
    __shared__ i64 sum_s[NACC];
    __shared__ float a_s[NINST][CCH];
    __shared__ float red[4];
    __shared__ float sconst[2];

    for (int i = tid; i < NACC; i += 256) {
        i64 s = 0;
        const i64* pp = partials + (size_t)b * NPIXBLK * NACC + i;
        for (int p = 0; p < NPIXBLK; p++) s += pp[(size_t)p * NACC];
        sum_s[i] = s;
    }
    __syncthreads();

    for (int i = tid; i < NINST * CCH; i += 256) {
        int n = i / CCH, c = i % CCH;
        float cntf = (float)sum_s[NINST * CCH + n] + EPSF;
        float raw = (float)((double)sum_s[i] * (1.0 / 4294967296.0));
        float a = raw / cntf * (1.f / 32.f);
        a_s[n][c] = a;
        centers[((size_t)b * NINST + n) * CCH + c] = a;
    }
    if (tid < NINST) countsf[b * NINST + tid] = (float)sum_s[NINST * CCH + tid];
    __syncthreads();

    for (int i = tid; i < NINST * NH; i += 256) {
        int n = i / NH, j = i % NH;
        float s = b1[j];
#pragma unroll
        for (int c = 0; c < CCH; c++) s += a_s[n][c] * W1[c * NH + j];
        qout[((size_t)b * NINST + n) * NH + j] = s;
    }
    float ma = 0.f;
    for (int i = tid; i < NINST * CCH; i += 256) ma = fmaxf(ma, fabsf(a_s[i / CCH][i % CCH]));
#pragma unroll
    for (int off = 32; off > 0; off >>= 1) ma = fmaxf(ma, __shfl_down(ma, off, 64));
    if ((tid & 63) == 0) red[tid >> 6] = ma;
    __syncthreads();
    if (tid == 0) {
        float m = fmaxf(fmaxf(red[0], red[1]), fmaxf(red[2], red[3]));
        meta[2 + b] = m;
        float Gs = 0.f;
        for (int n = 0; n < NINST; n++) Gs += (float)sum_s[NINST * CCH + n];
        meta[4 + b] = Gs;
        // conservative bound L on |logit|
        float L = fabsf(b2[0]);
        for (int j = 0; j < NH; j++) {
            float sa = 0.f;
            for (int c = 0; c < CCH; c++) sa += fabsf(W1[c * NH + j]);
            float hmax = fmaxf(b1[j] + 2.f * sa, 0.f);
            L += hmax * fabsf(W2[j]);
        }
        L += 1.f;  // margin
        float errlo = 1.f - L;
        float scale = (float)NBINS / (2.f * L);
        meta[0] = errlo;
        meta[1] = scale;
        sconst[0] = errlo;
        sconst[1] = scale;
    }
    __syncthreads();
    // padded-region items: emb=0 there, label=0, weight PADW per instance.
    // exact: feats = clip(a, -2, 2)
    if (tid < NINST) {
        int n = tid;
        float logit = b2[0];
        for (int j = 0; j < NH; j++) {
            float s = b1[j];
#pragma unroll
            for (int c = 0; c < CCH; c++) {
                float f = fminf(fmaxf(a_s[n][c], -2.f), 2.f);
                s += f * W1[c * NH + j];
            }
            logit += fmaxf(s, 0.f) * W2[j];
        }
        float e = 1.f + logit;  // label 0 -> sign -1
        float errlo = sconst[0], scale = sconst[1];
        int bin = (int)((e - errlo) * scale);
        bin = min(max(bin, 0), NBINS - 1);
        atomicAdd(&wg[(size_t)b * NBINS + bin], (u64)PADW);
    }
}

// One thread per interior pixel; loop over 32 instances; LDS-private
// histogram per block, single flush to global at the end.
// Small uniform tables (W1,b1,W2,b2,q,centers,meta) are read directly from
// global (wave-uniform -> s_load, L2-hot) to leave all 64KB LDS for the hist.
__global__ void __launch_bounds__(256, 2)
k_hist(const float* __restrict__ emb, const int* __restrict__ gt,
       const float* __restrict__ W1, const float* __restrict__ b1,
       const float* __restrict__ W2, const float* __restrict__ b2,
       const float* __restrict__ centers, const float* __restrict__ q,
       const float* __restrict__ meta,
       u64* __restrict__ wg) {
    __shared__ unsigned int hist[NBINS];  // 64 KB: w in low16, g in high16
    int b = blockIdx.y;
    int tid = threadIdx.x;
    for (int i = tid; i < NBINS; i += 256) hist[i] = 0u;
    __syncthreads();

    int pix = blockIdx.x * 256 + tid;
    const float* e = emb + (size_t)b * CCH * IMG_HW;
    int gtv = gt[(size_t)b * IMG_HW + pix];
    float u[CCH];
    float maxu = 0.f;
#pragma unroll
    for (int c = 0; c < CCH; c++) {
        u[c] = e[c * IMG_HW + pix] * (1.f / 32.f);
        maxu = fmaxf(maxu, fabsf(u[c]));
    }
    float b2v = b2[0];
    float errlo = meta[0], scale = meta[1], maxa = meta[2 + b];
    const float* qb = q + (size_t)b * NINST * NH;
    const float* ab = centers + (size_t)b * NINST * CCH;

    if (maxu + maxa <= 2.f) {
        // no element can clip: h = relu(q_n - v), v shared across instances
        float v[NH];
#pragma unroll
        for (int j = 0; j < NH; j++) {
            float s = 0.f;
#pragma unroll
            for (int c = 0; c < CCH; c++) s += u[c] * W1[c * NH + j];
            v[j] = s;
        }
        for (int n = 0; n < NINST; n++) {
            float logit = b2v;
#pragma unroll
            for (int j = 0; j < NH; j++) logit += fmaxf(qb[n * NH + j] - v[j], 0.f) * W2[j];
            unsigned int label = (gtv == n + 1) ? 1u : 0u;
            float er = label ? (1.f - logit) : (1.f + logit);
            int bin = (int)((er - errlo) * scale);
            bin = min(max(bin, 0), NBINS - 1);
            atomicAdd(&hist[bin], 1u | (label << 16));
        }
    } else {
        // exact slow path with per-element clip
        for (int n = 0; n < NINST; n++) {
            float logit = b2v;
            for (int j = 0; j < NH; j++) {
                float s = b1[j];
#pragma unroll
                for (int c = 0; c < CCH; c++) {
                    float f = fminf(fmaxf(ab[n * CCH + c] - u[c], -2.f), 2.f);
                    s += f * W1[c * NH + j];
                }
                logit += fmaxf(s, 0.f) * W2[j];
            }
            unsigned int label = (gtv == n + 1) ? 1u : 0u;
            float er = label ? (1.f - logit) : (1.f + logit);
            int bin = (int)((er - errlo) * scale);
            bin = min(max(bin, 0), NBINS - 1);
            atomicAdd(&hist[bin], 1u | (label << 16));
        }
    }
    __syncthreads();
    // flush nonzero bins to the global packed-u64 histogram
    u64* wgb = wg + (size_t)b * NBINS;
    for (int i = tid; i < NBINS; i += 256) {
        unsigned int h = hist[i];
        if (h) atomicAdd(&wgb[i], (u64)(h & 0xffffu) | ((u64)(h >> 16) << 32));
    }
}

// One block per image: scan bins in descending-error order, telescoping
// Jaccard contributions per bin. Each thread owns 16 consecutive bins.
// Per-bin representative error = bin center (error <= binwidth/2 ~ 2.6e-3).
__global__ void k_loss(const u64* __restrict__ wg,
                       const float* __restrict__ meta, float* __restrict__ out) {
    int b = blockIdx.x;
    int tid = threadIdx.x;
    const u64* wgb = wg + (size_t)b * NBINS;
    double G = (double)meta[4 + b];
    double errlo = (double)meta[0];
    double invscale = 1.0 / (double)meta[1];
    const int BPT = NBINS / 1024;

    // pass 1: per-thread packed totals over its BPT bins
    u64 tot = 0;
    for (int k = 0; k < BPT; k++) {
        int bin = NBINS - 1 - (tid * BPT + k);
        tot += wgb[bin];
    }
    // wave-level inclusive scan
    u64 incl = tot;
    int lane = tid & 63, wid = tid >> 6;
#pragma unroll
    for (int off = 1; off < 64; off <<= 1) {
        u64 x = __shfl_up(incl, off, 64);
        if (lane >= off) incl += x;
    }
    __shared__ u64 wpart[16];
    __shared__ double lossred[16];
    if (lane == 63) wpart[wid] = incl;
    __syncthreads();
    u64 woff = 0;
    for (int w = 0; w < wid; w++) woff += wpart[w];
    u64 excl = woff + incl - tot;
    unsigned int p = (unsigned int)(excl & 0xffffffffull);
    unsigned int cs = (unsigned int)(excl >> 32);

    // pass 2: contributions
    double loss = 0.0;
    if (G > 0.5) {
        for (int k = 0; k < BPT; k++) {
            int bin = NBINS - 1 - (tid * BPT + k);
            u64 v = wgb[bin];
            unsigned int w = (unsigned int)(v & 0xffffffffull);
            unsigned int g = (unsigned int)(v >> 32);
            if (w) {
                double Js = 1.0 - (G - (double)cs) / (G + (double)p - (double)cs);
                unsigned int pe = p + w, ce = cs + g;
                double Je = 1.0 - (G - (double)ce) / (G + (double)pe - (double)ce);
                double rep = errlo + ((double)bin + 0.5) * invscale;
                if (rep < 0.0) rep = 0.0;
                loss += rep * (Je - Js);
                p = pe;
                cs = ce;
            }
        }
    }
#pragma unroll
    for (int off = 32; off > 0; off >>= 1) loss += __shfl_down(loss, off, 64);
    if (lane == 0) lossred[wid] = loss;
    __syncthreads();
    if (tid == 0) {
        double t = 0;
        for (int w = 0; w < 16; w++) t += lossred[w];
        atomicAdd(out, (float)(t * 0.5));  // mean over 2 images
    }
}

extern "C" void kernel_launch(void* const* d_in, const int* in_sizes, int n_in,
                              void* d_out, int out_size, void* d_ws, size_t ws_size,
                              hipStream_t stream) {
    const float* emb = (const float*)d_in[0];
    const int* gt = (const int*)d_in[1];
    const float* W1 = (const float*)d_in[2];
    const float* b1 = (const float*)d_in[3];
    const float* W2 = (const float*)d_in[4];
    const float* b2 = (const float*)d_in[5];
    float* out = (float*)d_out;
    char* ws = (char*)d_ws;

    u64* wg = (u64*)(ws + OFF_WG);
    i64* partials = (i64*)(ws + OFF_PART);
    float* centers = (float*)(ws + OFF_CENT);
    float* q = (float*)(ws + OFF_Q);
    float* countsf = (float*)(ws + OFF_CNT);
    float* meta = (float*)(ws + OFF_META);

    k_centers<<<dim3(NPIXBLK, NB), 256, 0, stream>>>(emb, gt, partials, wg, out);
    k_finalize<<<dim3(NB), 256, 0, stream>>>(W1, b1, W2, b2, partials, centers, countsf, q, meta, wg);
    k_hist<<<dim3(NPIXBLK, NB), 256, 0, stream>>>(emb, gt, W1, b1, W2, b2, centers, q, meta, wg);
    k_loss<<<dim3(NB), 1024, 0, stream>>>(wg, meta, out);
}